// Round 3
// baseline (127.197 us; speedup 1.0000x reference)
//
#include <hip/hip_runtime.h>
#include <math.h>

#define BLK 256
#define RPT 4                     // rows per thread: 4 rows * 7 f32 = 7 float4

// ---------------------------------------------------------------------------
// Rotated-box intersection area via Green's theorem (no polygon clipping):
// area(P∩Q) = 1/2 ∮ (x dy − y dx) = Σ P-edge pieces clipped to Q's AAB frame
// + Σ Q-edge pieces clipped to P's AAB frame + 1/2·cross(t, R·ΣΔ) translation
// correction.  Each piece is a branchless Liang-Barsky slab clip.
//
// Memory structure (this revision): thread→data remap for full vectorization
// with NO LDS and NO barrier. Each thread owns 4 consecutive rows of one
// batch: 28 floats = 7 exactly-16B-aligned float4 per array (112 = 7*16).
// box_preds / reg_targets / anchors load as 7x dwordx4 each; iou/one_hot/
// weights/out collapse to one float4/int4 per thread. Per-pair VMEM instrs
// drop ~15.5 -> 6, issue density 4 B/instr -> 16 B/instr, and each wave reads
// one dense contiguous 7 KiB span per array instead of 5 strided passes.
// NT hints REMOVED (round-2: bypassing L1/L2 broke same-line reuse, +10 us).
// LDS staging REMOVED (round-1: barrier vmcnt-drain broke MLP overlap).
// All local arrays fully unrolled / statically indexed -> stay in VGPRs.
// Anchor reuse across the B=4 y-blocks happens in L2 (same XCD: x-stride
// 256 ≡ 0 mod 8), not in registers.
// ---------------------------------------------------------------------------

__device__ __forceinline__ float clamp_mag(float x) {
    return copysignf(fmaxf(fabsf(x), 1e-30f), x);
}

// clip segment p + s*e, s in [0,1], to box [-hx,hx] x [-hy,hy]; r = 1/e (pre-clamped)
__device__ __forceinline__ void edge_piece(float px, float py, float ex, float ey,
                                           float rx, float ry, float hx, float hy,
                                           float& area2, float& Dx, float& Dy)
{
    float sx0 = (-hx - px) * rx, sx1 = (hx - px) * rx;
    float sy0 = (-hy - py) * ry, sy1 = (hy - py) * ry;
    float smin = fmaxf(fmaxf(fminf(sx0, sx1), fminf(sy0, sy1)), 0.0f);
    float smax = fminf(fminf(fmaxf(sx0, sx1), fmaxf(sy0, sy1)), 1.0f);
    smax = fmaxf(smax, smin);                  // empty -> zero-length at smin
    float ax = fmaf(smin, ex, px), ay = fmaf(smin, ey, py);
    float bx = fmaf(smax, ex, px), by = fmaf(smax, ey, py);
    float ux = bx - ax, uy = by - ay;          // exactly 0 when smin==smax
    area2 += fmaf(ax, uy, -(ay * ux));         // cross(a, b-a) == cross(a,b)
    Dx += ux; Dy += uy;
}

// Full pair IoU -> loss for one (pred, target) box pair sharing an anchor.
__device__ __forceinline__ float pair_loss(const float bp[5], const float rt[5],
                                           float xa, float ya, float dxa, float dya,
                                           float ra, float diag,
                                           float ip, int oh, float w)
{
    // decode P (pred) / Q (target): fields {x, y, dx, dy, r}
    float x1  = fmaf(bp[0], diag, xa);
    float y1  = fmaf(bp[1], diag, ya);
    float dx1 = __expf(bp[2]) * dxa;
    float dy1 = __expf(bp[3]) * dya;
    float r1  = bp[4] + ra;

    float x2  = fmaf(rt[0], diag, xa);
    float y2  = fmaf(rt[1], diag, ya);
    float dx2 = __expf(rt[2]) * dxa;
    float dy2 = __expf(rt[3]) * dya;
    float r2  = rt[4] + ra;

    float a1 = dx1 * dy1, a2 = dx2 * dy2;
    float h1x = 0.5f * dx1, h1y = 0.5f * dy1;
    float h2x = 0.5f * dx2, h2y = 0.5f * dy2;

    // P in Q's frame: p_Q = R(dr)·p_P + t
    float c2v = __cosf(r2), s2v = __sinf(r2);
    float dr  = r1 - r2;
    float cd  = __cosf(dr), sd = __sinf(dr);
    float ddx = x1 - x2, ddy = y1 - y2;
    float tx  = fmaf(c2v, ddx,  s2v * ddy);
    float ty  = fmaf(-s2v, ddx, c2v * ddy);

    // P half-edge vectors in Q frame
    float ux_ = h1x * cd,  uy_ = h1x * sd;
    float vx_ = -h1y * sd, vy_ = h1y * cd;
    // full edge vectors ±2u, ±2v and their shared reciprocals
    float eux = 2.0f * ux_, euy = 2.0f * uy_;
    float evx = 2.0f * vx_, evy = 2.0f * vy_;
    float ruxP = __fdividef(1.0f, clamp_mag(eux));
    float ruyP = __fdividef(1.0f, clamp_mag(euy));
    float rvxP = __fdividef(1.0f, clamp_mag(evx));
    float rvyP = __fdividef(1.0f, clamp_mag(evy));
    // corners (CCW)
    float p0x = tx + ux_ + vx_, p0y = ty + uy_ + vy_;
    float p1x = tx - ux_ + vx_, p1y = ty - uy_ + vy_;
    float p2x = tx - ux_ - vx_, p2y = ty - uy_ - vy_;
    float p3x = tx + ux_ - vx_, p3y = ty + uy_ - vy_;

    float area2 = 0.0f, dDx = 0.0f, dDy = 0.0f;
    edge_piece(p0x, p0y, -eux, -euy, -ruxP, -ruyP, h2x, h2y, area2, dDx, dDy);
    edge_piece(p1x, p1y, -evx, -evy, -rvxP, -rvyP, h2x, h2y, area2, dDx, dDy);
    edge_piece(p2x, p2y,  eux,  euy,  ruxP,  ruyP, h2x, h2y, area2, dDx, dDy);
    edge_piece(p3x, p3y,  evx,  evy,  rvxP,  rvyP, h2x, h2y, area2, dDx, dDy);

    // Q in P's frame: u' = R^T·(h2x,0), v' = R^T·(0,h2y), o = -R^T·t
    float upx = h2x * cd,  upy = -h2x * sd;
    float vpx = h2y * sd,  vpy = h2y * cd;
    float ox  = -(fmaf(cd, tx,  sd * ty));
    float oy  = -(fmaf(-sd, tx, cd * ty));
    float equx = 2.0f * upx, equy = 2.0f * upy;
    float eqvx = 2.0f * vpx, eqvy = 2.0f * vpy;
    float ruxQ = __fdividef(1.0f, clamp_mag(equx));
    float ruyQ = __fdividef(1.0f, clamp_mag(equy));
    float rvxQ = __fdividef(1.0f, clamp_mag(eqvx));
    float rvyQ = __fdividef(1.0f, clamp_mag(eqvy));
    float q0x = ox + upx + vpx, q0y = oy + upy + vpy;
    float q1x = ox - upx + vpx, q1y = oy - upy + vpy;
    float q2x = ox - upx - vpx, q2y = oy - upy - vpy;
    float q3x = ox + upx - vpx, q3y = oy + upy - vpy;

    float Dx = 0.0f, Dy = 0.0f;
    edge_piece(q0x, q0y, -equx, -equy, -ruxQ, -ruyQ, h1x, h1y, area2, Dx, Dy);
    edge_piece(q1x, q1y, -eqvx, -eqvy, -rvxQ, -rvyQ, h1x, h1y, area2, Dx, Dy);
    edge_piece(q2x, q2y,  equx,  equy,  ruxQ,  ruyQ, h1x, h1y, area2, Dx, Dy);
    edge_piece(q3x, q3y,  eqvx,  eqvy,  rvxQ,  rvyQ, h1x, h1y, area2, Dx, Dy);

    // translation correction: cross(t, R·D)
    float RDx = fmaf(cd, Dx, -(sd * Dy));
    float RDy = fmaf(sd, Dx,   cd * Dy);
    area2 += fmaf(tx, RDy, -(ty * RDx));

    float inter = 0.5f * fabsf(area2);
    float uni = fmaxf(a1 + a2 - inter, 1e-6f);
    float iou = __fdividef(inter, uni);

    float target = (oh > 0) ? iou : 0.0f;
    float z  = __fdividef(1.0f, 1.0f + __expf(-ip));   // sigmoid
    float pt = __logf(1.0f + __expf(z)) - z * target;  // logaddexp(0,z) - z*target
    return pt * w;
}

__global__ __launch_bounds__(BLK)
void iou_pred_loss_kernel(const float* __restrict__ iou_preds,
                          const int*   __restrict__ one_hot,
                          const float* __restrict__ weights,
                          const float* __restrict__ anchors,
                          const float* __restrict__ box_preds,
                          const float* __restrict__ reg_targets,
                          float* __restrict__ out,
                          int N, int B)
{
    int tid  = threadIdx.x;
    int row0 = (blockIdx.x * BLK + tid) * RPT;
    if (row0 >= N) return;
    int b = blockIdx.y;
    size_t g0 = (size_t)b * N + row0;

    if (row0 + RPT <= N) {
        // ---- fast path: fully-vectorized loads, all issued up front ----
        const float4* bp4 = (const float4*)(box_preds   + g0 * 7);
        const float4* rt4 = (const float4*)(reg_targets + g0 * 7);
        const float4* an4 = (const float4*)(anchors + (size_t)row0 * 7);

        float fb[28], fr[28], fa[28];
        #pragma unroll
        for (int k = 0; k < 7; ++k) {
            float4 t = bp4[k];
            fb[4*k+0] = t.x; fb[4*k+1] = t.y; fb[4*k+2] = t.z; fb[4*k+3] = t.w;
        }
        #pragma unroll
        for (int k = 0; k < 7; ++k) {
            float4 t = rt4[k];
            fr[4*k+0] = t.x; fr[4*k+1] = t.y; fr[4*k+2] = t.z; fr[4*k+3] = t.w;
        }
        #pragma unroll
        for (int k = 0; k < 7; ++k) {
            float4 t = an4[k];
            fa[4*k+0] = t.x; fa[4*k+1] = t.y; fa[4*k+2] = t.z; fa[4*k+3] = t.w;
        }
        float4 ip4 = *(const float4*)(iou_preds + g0);
        int4   oh4 = *(const int4*)  (one_hot   + g0);
        float4 w4  = *(const float4*)(weights   + g0);
        float ipv[RPT] = {ip4.x, ip4.y, ip4.z, ip4.w};
        int   ohv[RPT] = {oh4.x, oh4.y, oh4.z, oh4.w};
        float wv[RPT]  = {w4.x,  w4.y,  w4.z,  w4.w};

        float res[RPT];
        #pragma unroll
        for (int r = 0; r < RPT; ++r) {          // all indices compile-time
            float xa  = fa[7*r+0], ya  = fa[7*r+1];
            float dxa = fa[7*r+3], dya = fa[7*r+4], ra = fa[7*r+6];
            float diag = sqrtf(fmaf(dxa, dxa, dya * dya));
            float bp[5] = {fb[7*r+0], fb[7*r+1], fb[7*r+3], fb[7*r+4], fb[7*r+6]};
            float rt[5] = {fr[7*r+0], fr[7*r+1], fr[7*r+3], fr[7*r+4], fr[7*r+6]};
            res[r] = pair_loss(bp, rt, xa, ya, dxa, dya, ra, diag,
                               ipv[r], ohv[r], wv[r]);
        }
        float4 o = {res[0], res[1], res[2], res[3]};
        *(float4*)(out + g0) = o;
    } else {
        // ---- tail (not hit when N % 4 == 0): scalar per row ----
        for (int r = 0; r < RPT && row0 + r < N; ++r) {
            size_t g = g0 + r;
            const float* bpp = box_preds   + g * 7;
            const float* rtp = reg_targets + g * 7;
            const float* an  = anchors + (size_t)(row0 + r) * 7;
            float bp[5] = {bpp[0], bpp[1], bpp[3], bpp[4], bpp[6]};
            float rt[5] = {rtp[0], rtp[1], rtp[3], rtp[4], rtp[6]};
            float xa = an[0], ya = an[1], dxa = an[3], dya = an[4], ra = an[6];
            float diag = sqrtf(fmaf(dxa, dxa, dya * dya));
            out[g] = pair_loss(bp, rt, xa, ya, dxa, dya, ra, diag,
                               iou_preds[g], one_hot[g], weights[g]);
        }
    }
}

extern "C" void kernel_launch(void* const* d_in, const int* in_sizes, int n_in,
                              void* d_out, int out_size, void* d_ws, size_t ws_size,
                              hipStream_t stream) {
    const float* iou_preds   = (const float*)d_in[0];
    const int*   one_hot     = (const int*)  d_in[1];
    const float* weights     = (const float*)d_in[2];
    const float* anchors     = (const float*)d_in[3];
    const float* box_preds   = (const float*)d_in[4];
    const float* reg_targets = (const float*)d_in[5];
    float* out = (float*)d_out;

    int total = in_sizes[0];       // B*N
    int N     = in_sizes[3] / 7;   // anchor count
    int B     = total / N;

    int rows_per_block = BLK * RPT;
    dim3 grid((N + rows_per_block - 1) / rows_per_block, B);
    iou_pred_loss_kernel<<<grid, dim3(BLK), 0, stream>>>(
        iou_preds, one_hot, weights, anchors, box_preds, reg_targets,
        out, N, B);
}

// Round 4
// 113.085 us; speedup vs baseline: 1.1248x; 1.1248x over previous
//
#include <hip/hip_runtime.h>
#include <math.h>

#define BLK 256
#define WVS (BLK / 64)            // 4 waves per block
#define TW  448                   // floats per tile: 64 rows * 7 f32 = 1792 B
#define NARR 5                    // bp0, rt0, bp1, rt1, anchors

// ---------------------------------------------------------------------------
// Rotated-box intersection area via Green's theorem (branchless Liang-Barsky
// slab clips; see earlier revisions for the math derivation).
//
// Memory structure (this revision): WAVE-PRIVATE LDS staging, NO barrier.
// Evidence trail:
//   r0 baseline (scalar strided MLP loads)     kernel ~29 us
//   r1 block LDS staging + __syncthreads       +3 us  (barrier vmcnt-drain)
//   r2 non-temporal                            +10 us (broke line reuse)
//   r3 4-rows/thread float4 (112B lane stride) +16 us (64 segs/instr — worse!)
// r3's regression mechanism proves the kernel is TA/segment-bound (~730
// 64B-segments per wave at ~1/cyc/CU ≈ 29 us; HBM bytes only ~13 us).
// Fix: each wave stages its OWN 64 rows (1792 B/array) with 2 dwordx4
// wave-instructions per array (lane-contiguous -> 28 segments, each line
// touched once) into a wave-private LDS slice, then reads rows back.
// Same-wave LDS write->read is ordered by compiler-inserted lgkmcnt —
// NO __syncthreads, so cross-wave MLP overlap is preserved (r1's failure
// mode avoided). Segments/wave: ~730 -> ~172. Thread->row map unchanged
// from r0 (lane L of wave w = row bx*256 + w*64 + L = bx*256 + tid).
// LDS reads at word stride 7: lanes t/t+32 differ by 224 ≡ 0 mod 32 ->
// 2 lanes/bank, free on gfx950 (m136).
// ---------------------------------------------------------------------------

__device__ __forceinline__ float clamp_mag(float x) {
    return copysignf(fmaxf(fabsf(x), 1e-30f), x);
}

// clip segment p + s*e, s in [0,1], to box [-hx,hx] x [-hy,hy]; r = 1/e (pre-clamped)
__device__ __forceinline__ void edge_piece(float px, float py, float ex, float ey,
                                           float rx, float ry, float hx, float hy,
                                           float& area2, float& Dx, float& Dy)
{
    float sx0 = (-hx - px) * rx, sx1 = (hx - px) * rx;
    float sy0 = (-hy - py) * ry, sy1 = (hy - py) * ry;
    float smin = fmaxf(fmaxf(fminf(sx0, sx1), fminf(sy0, sy1)), 0.0f);
    float smax = fminf(fminf(fmaxf(sx0, sx1), fmaxf(sy0, sy1)), 1.0f);
    smax = fmaxf(smax, smin);                  // empty -> zero-length at smin
    float ax = fmaf(smin, ex, px), ay = fmaf(smin, ey, py);
    float bx = fmaf(smax, ex, px), by = fmaf(smax, ey, py);
    float ux = bx - ax, uy = by - ay;          // exactly 0 when smin==smax
    area2 += fmaf(ax, uy, -(ay * ux));         // cross(a, b-a) == cross(a,b)
    Dx += ux; Dy += uy;
}

// Full pair IoU -> loss for one (pred, target) box pair sharing an anchor.
__device__ __forceinline__ float pair_loss(const float bp[5], const float rt[5],
                                           float xa, float ya, float dxa, float dya,
                                           float ra, float diag,
                                           float ip, int oh, float w)
{
    // decode P (pred) / Q (target): fields {x, y, dx, dy, r}
    float x1  = fmaf(bp[0], diag, xa);
    float y1  = fmaf(bp[1], diag, ya);
    float dx1 = __expf(bp[2]) * dxa;
    float dy1 = __expf(bp[3]) * dya;
    float r1  = bp[4] + ra;

    float x2  = fmaf(rt[0], diag, xa);
    float y2  = fmaf(rt[1], diag, ya);
    float dx2 = __expf(rt[2]) * dxa;
    float dy2 = __expf(rt[3]) * dya;
    float r2  = rt[4] + ra;

    float a1 = dx1 * dy1, a2 = dx2 * dy2;
    float h1x = 0.5f * dx1, h1y = 0.5f * dy1;
    float h2x = 0.5f * dx2, h2y = 0.5f * dy2;

    // P in Q's frame: p_Q = R(dr)·p_P + t
    float c2v = __cosf(r2), s2v = __sinf(r2);
    float dr  = r1 - r2;
    float cd  = __cosf(dr), sd = __sinf(dr);
    float ddx = x1 - x2, ddy = y1 - y2;
    float tx  = fmaf(c2v, ddx,  s2v * ddy);
    float ty  = fmaf(-s2v, ddx, c2v * ddy);

    // P half-edge vectors in Q frame
    float ux_ = h1x * cd,  uy_ = h1x * sd;
    float vx_ = -h1y * sd, vy_ = h1y * cd;
    float eux = 2.0f * ux_, euy = 2.0f * uy_;
    float evx = 2.0f * vx_, evy = 2.0f * vy_;
    float ruxP = __fdividef(1.0f, clamp_mag(eux));
    float ruyP = __fdividef(1.0f, clamp_mag(euy));
    float rvxP = __fdividef(1.0f, clamp_mag(evx));
    float rvyP = __fdividef(1.0f, clamp_mag(evy));
    float p0x = tx + ux_ + vx_, p0y = ty + uy_ + vy_;
    float p1x = tx - ux_ + vx_, p1y = ty - uy_ + vy_;
    float p2x = tx - ux_ - vx_, p2y = ty - uy_ - vy_;
    float p3x = tx + ux_ - vx_, p3y = ty + uy_ - vy_;

    float area2 = 0.0f, dDx = 0.0f, dDy = 0.0f;
    edge_piece(p0x, p0y, -eux, -euy, -ruxP, -ruyP, h2x, h2y, area2, dDx, dDy);
    edge_piece(p1x, p1y, -evx, -evy, -rvxP, -rvyP, h2x, h2y, area2, dDx, dDy);
    edge_piece(p2x, p2y,  eux,  euy,  ruxP,  ruyP, h2x, h2y, area2, dDx, dDy);
    edge_piece(p3x, p3y,  evx,  evy,  rvxP,  rvyP, h2x, h2y, area2, dDx, dDy);

    // Q in P's frame
    float upx = h2x * cd,  upy = -h2x * sd;
    float vpx = h2y * sd,  vpy = h2y * cd;
    float ox  = -(fmaf(cd, tx,  sd * ty));
    float oy  = -(fmaf(-sd, tx, cd * ty));
    float equx = 2.0f * upx, equy = 2.0f * upy;
    float eqvx = 2.0f * vpx, eqvy = 2.0f * vpy;
    float ruxQ = __fdividef(1.0f, clamp_mag(equx));
    float ruyQ = __fdividef(1.0f, clamp_mag(equy));
    float rvxQ = __fdividef(1.0f, clamp_mag(eqvx));
    float rvyQ = __fdividef(1.0f, clamp_mag(eqvy));
    float q0x = ox + upx + vpx, q0y = oy + upy + vpy;
    float q1x = ox - upx + vpx, q1y = oy - upy + vpy;
    float q2x = ox - upx - vpx, q2y = oy - upy - vpy;
    float q3x = ox + upx - vpx, q3y = oy + upy - vpy;

    float Dx = 0.0f, Dy = 0.0f;
    edge_piece(q0x, q0y, -equx, -equy, -ruxQ, -ruyQ, h1x, h1y, area2, Dx, Dy);
    edge_piece(q1x, q1y, -eqvx, -eqvy, -rvxQ, -rvyQ, h1x, h1y, area2, Dx, Dy);
    edge_piece(q2x, q2y,  equx,  equy,  ruxQ,  ruyQ, h1x, h1y, area2, Dx, Dy);
    edge_piece(q3x, q3y,  eqvx,  eqvy,  rvxQ,  rvyQ, h1x, h1y, area2, Dx, Dy);

    // translation correction: cross(t, R·D)
    float RDx = fmaf(cd, Dx, -(sd * Dy));
    float RDy = fmaf(sd, Dx,   cd * Dy);
    area2 += fmaf(tx, RDy, -(ty * RDx));

    float inter = 0.5f * fabsf(area2);
    float uni = fmaxf(a1 + a2 - inter, 1e-6f);
    float iou = __fdividef(inter, uni);

    float target = (oh > 0) ? iou : 0.0f;
    float z  = __fdividef(1.0f, 1.0f + __expf(-ip));   // sigmoid
    float pt = __logf(1.0f + __expf(z)) - z * target;  // logaddexp(0,z) - z*target
    return pt * w;
}

__global__ __launch_bounds__(BLK)
void iou_pred_loss_kernel(const float* __restrict__ iou_preds,
                          const int*   __restrict__ one_hot,
                          const float* __restrict__ weights,
                          const float* __restrict__ anchors,
                          const float* __restrict__ box_preds,
                          const float* __restrict__ reg_targets,
                          float* __restrict__ out,
                          int N, int B)
{
    // wave-private tiles: [wave][array][448 floats]; no padding needed
    __shared__ float s_lds[WVS * NARR * TW];

    int tid  = threadIdx.x;
    int lane = tid & 63;
    int wid  = tid >> 6;

    int yspan = gridDim.y;                 // = ceil(B/2)
    int b0 = blockIdx.y;
    int b1 = blockIdx.y + yspan;
    bool has2 = (b1 < B);
    int b1c = has2 ? b1 : b0;

    int n_idx = blockIdx.x * BLK + tid;    // this thread's row
    bool full_block = (blockIdx.x * BLK + BLK) <= N;

    if (full_block) {
        int wrow0 = blockIdx.x * BLK + wid * 64;   // wave's first row

        // ---- wave-cooperative tile loads: 2 dwordx4 instrs per array,
        //      lane-contiguous (28 segments/array, each line once) ----
        const float4* pb0 = (const float4*)(box_preds   + ((size_t)b0  * N + wrow0) * 7);
        const float4* pr0 = (const float4*)(reg_targets + ((size_t)b0  * N + wrow0) * 7);
        const float4* pb1 = (const float4*)(box_preds   + ((size_t)b1c * N + wrow0) * 7);
        const float4* pr1 = (const float4*)(reg_targets + ((size_t)b1c * N + wrow0) * 7);
        const float4* pan = (const float4*)(anchors     + ((size_t)wrow0) * 7);

        bool second = lane < (TW / 4 - 64);        // 112 - 64 = 48 lanes
        int  l2 = 64 + lane;

        // issue ALL global loads up front (MLP), then write to LDS
        float4 a0 = pb0[lane], a1 = pr0[lane], a2 = pb1[lane], a3 = pr1[lane], a4 = pan[lane];
        float4 c0, c1, c2, c3, c4;
        if (second) { c0 = pb0[l2]; c1 = pr0[l2]; c2 = pb1[l2]; c3 = pr1[l2]; c4 = pan[l2]; }

        // coalesced per-thread scalars (4 lines per wave-instr)
        size_t g0 = (size_t)b0  * N + n_idx;
        size_t g1 = (size_t)b1c * N + n_idx;
        float ip0 = iou_preds[g0], ip1 = iou_preds[g1];
        int   oh0 = one_hot[g0],   oh1 = one_hot[g1];
        float w0  = weights[g0],   w1  = weights[g1];

        float4* t0 = (float4*)&s_lds[(wid * NARR + 0) * TW];
        float4* t1 = (float4*)&s_lds[(wid * NARR + 1) * TW];
        float4* t2 = (float4*)&s_lds[(wid * NARR + 2) * TW];
        float4* t3 = (float4*)&s_lds[(wid * NARR + 3) * TW];
        float4* t4 = (float4*)&s_lds[(wid * NARR + 4) * TW];
        t0[lane] = a0; t1[lane] = a1; t2[lane] = a2; t3[lane] = a3; t4[lane] = a4;
        if (second) { t0[l2] = c0; t1[l2] = c1; t2[l2] = c2; t3[l2] = c3; t4[l2] = c4; }
        // NO __syncthreads: tiles are wave-private; same-wave LDS write->read
        // is ordered by compiler-inserted lgkmcnt.

        int lw = lane * 7;
        const float* f0 = &s_lds[(wid * NARR + 0) * TW];
        const float* f1 = &s_lds[(wid * NARR + 1) * TW];
        const float* f2 = &s_lds[(wid * NARR + 2) * TW];
        const float* f3 = &s_lds[(wid * NARR + 3) * TW];
        const float* f4 = &s_lds[(wid * NARR + 4) * TW];

        float xa = f4[lw + 0], ya = f4[lw + 1];
        float dxa = f4[lw + 3], dya = f4[lw + 4], ra = f4[lw + 6];
        float diag = sqrtf(fmaf(dxa, dxa, dya * dya));

        {
            float bp[5] = { f0[lw+0], f0[lw+1], f0[lw+3], f0[lw+4], f0[lw+6] };
            float rt[5] = { f1[lw+0], f1[lw+1], f1[lw+3], f1[lw+4], f1[lw+6] };
            out[g0] = pair_loss(bp, rt, xa, ya, dxa, dya, ra, diag, ip0, oh0, w0);
        }
        if (has2) {
            float bp[5] = { f2[lw+0], f2[lw+1], f2[lw+3], f2[lw+4], f2[lw+6] };
            float rt[5] = { f3[lw+0], f3[lw+1], f3[lw+3], f3[lw+4], f3[lw+6] };
            out[g1] = pair_loss(bp, rt, xa, ya, dxa, dya, ra, diag, ip1, oh1, w1);
        }
    } else if (n_idx < N) {
        // ---- tail block (not hit when N % 256 == 0): r0 scalar path ----
        size_t g0 = (size_t)b0  * N + n_idx;
        size_t g1 = (size_t)b1c * N + n_idx;
        const float* an = anchors + (size_t)n_idx * 7;
        float xa = an[0], ya = an[1], dxa = an[3], dya = an[4], ra = an[6];
        float diag = sqrtf(fmaf(dxa, dxa, dya * dya));

        const float* bpp0 = box_preds   + g0 * 7;
        const float* rtp0 = reg_targets + g0 * 7;
        float bp0[5] = {bpp0[0], bpp0[1], bpp0[3], bpp0[4], bpp0[6]};
        float rt0[5] = {rtp0[0], rtp0[1], rtp0[3], rtp0[4], rtp0[6]};
        out[g0] = pair_loss(bp0, rt0, xa, ya, dxa, dya, ra, diag,
                            iou_preds[g0], one_hot[g0], weights[g0]);
        if (has2) {
            const float* bpp1 = box_preds   + g1 * 7;
            const float* rtp1 = reg_targets + g1 * 7;
            float bp1[5] = {bpp1[0], bpp1[1], bpp1[3], bpp1[4], bpp1[6]};
            float rt1[5] = {rtp1[0], rtp1[1], rtp1[3], rtp1[4], rtp1[6]};
            out[g1] = pair_loss(bp1, rt1, xa, ya, dxa, dya, ra, diag,
                                iou_preds[g1], one_hot[g1], weights[g1]);
        }
    }
}

extern "C" void kernel_launch(void* const* d_in, const int* in_sizes, int n_in,
                              void* d_out, int out_size, void* d_ws, size_t ws_size,
                              hipStream_t stream) {
    const float* iou_preds   = (const float*)d_in[0];
    const int*   one_hot     = (const int*)  d_in[1];
    const float* weights     = (const float*)d_in[2];
    const float* anchors     = (const float*)d_in[3];
    const float* box_preds   = (const float*)d_in[4];
    const float* reg_targets = (const float*)d_in[5];
    float* out = (float*)d_out;

    int total = in_sizes[0];       // B*N
    int N     = in_sizes[3] / 7;   // anchor count
    int B     = total / N;

    dim3 grid((N + BLK - 1) / BLK, (B + 1) / 2);
    iou_pred_loss_kernel<<<grid, dim3(BLK), 0, stream>>>(
        iou_preds, one_hot, weights, anchors, box_preds, reg_targets,
        out, N, B);
}

// Round 5
// 111.630 us; speedup vs baseline: 1.1395x; 1.0130x over previous
//
#include <hip/hip_runtime.h>
#include <math.h>

#define BLK 256

// ---------------------------------------------------------------------------
// Rotated-box intersection area via Green's theorem (no polygon clipping):
// area(P∩Q) = 1/2 ∮ (x dy − y dx) = Σ P-edge pieces clipped to Q's AAB frame
// + Σ Q-edge pieces clipped to P's AAB frame + 1/2·cross(t, R·ΣΔ) translation
// correction (x dy − y dx is rotation-invariant).  Each piece is a branchless
// Liang-Barsky slab clip; empty clips give exactly-zero-length pieces.
//
// FINAL STRUCTURE (reverted to the measured-best r0 after 4 falsifying
// experiments). Evidence trail (kernel-only time = bench − ~82 us fills):
//   r0 scalar strided MLP loads, 2 batches/thread   ~29 us  <- best
//   r1 block LDS staging + __syncthreads            ~32 us  (barrier drain)
//   r2 non-temporal loads                           ~39 us  (broke line reuse)
//   r3 4-rows/thread float4, 112B lane stride       ~45 us  (64 segs/instr)
//   r4 wave-private LDS, barrierless, segs/wave /4  ~31 us  (neutral!)
// r4 falsified the transaction-bound theory: cutting 64B-segments 4.3x
// changed nothing. Byte floor = 82.8 MB @ 6.3 TB/s ~= 13 us, VALU ~= 5 us
// (overlapped); the residual is dispatch ramp + mixed 7-stream DRAM
// efficiency on a ~29 us kernel — not movable from source. The bench's
// other ~82 us is two 268 MB harness re-poison fills (fixed cost).
//
// Structure notes: each thread processes the SAME anchor row for 2 batches
// (anchor load + diag amortized); all global loads issued up front (MLP);
// (x,0)/(x,1) y-slices are 1024 blocks apart in dispatch order, 1024 % 8 == 0
// -> same XCD -> anchor re-reads hit the same L2.
// ---------------------------------------------------------------------------

__device__ __forceinline__ float clamp_mag(float x) {
    return copysignf(fmaxf(fabsf(x), 1e-30f), x);
}

// clip segment p + s*e, s in [0,1], to box [-hx,hx] x [-hy,hy]; r = 1/e (pre-clamped)
__device__ __forceinline__ void edge_piece(float px, float py, float ex, float ey,
                                           float rx, float ry, float hx, float hy,
                                           float& area2, float& Dx, float& Dy)
{
    float sx0 = (-hx - px) * rx, sx1 = (hx - px) * rx;
    float sy0 = (-hy - py) * ry, sy1 = (hy - py) * ry;
    float smin = fmaxf(fmaxf(fminf(sx0, sx1), fminf(sy0, sy1)), 0.0f);
    float smax = fminf(fminf(fmaxf(sx0, sx1), fmaxf(sy0, sy1)), 1.0f);
    smax = fmaxf(smax, smin);                  // empty -> zero-length at smin
    float ax = fmaf(smin, ex, px), ay = fmaf(smin, ey, py);
    float bx = fmaf(smax, ex, px), by = fmaf(smax, ey, py);
    float ux = bx - ax, uy = by - ay;          // exactly 0 when smin==smax
    area2 += fmaf(ax, uy, -(ay * ux));         // cross(a, b-a) == cross(a,b)
    Dx += ux; Dy += uy;
}

// Full pair IoU -> loss for one (pred, target) box pair sharing an anchor.
__device__ __forceinline__ float pair_loss(const float bp[5], const float rt[5],
                                           float xa, float ya, float dxa, float dya,
                                           float ra, float diag,
                                           float ip, int oh, float w)
{
    // decode P (pred) / Q (target): fields {x, y, dx, dy, r}
    float x1  = fmaf(bp[0], diag, xa);
    float y1  = fmaf(bp[1], diag, ya);
    float dx1 = __expf(bp[2]) * dxa;
    float dy1 = __expf(bp[3]) * dya;
    float r1  = bp[4] + ra;

    float x2  = fmaf(rt[0], diag, xa);
    float y2  = fmaf(rt[1], diag, ya);
    float dx2 = __expf(rt[2]) * dxa;
    float dy2 = __expf(rt[3]) * dya;
    float r2  = rt[4] + ra;

    float a1 = dx1 * dy1, a2 = dx2 * dy2;
    float h1x = 0.5f * dx1, h1y = 0.5f * dy1;
    float h2x = 0.5f * dx2, h2y = 0.5f * dy2;

    // P in Q's frame: p_Q = R(dr)·p_P + t
    float c2v = __cosf(r2), s2v = __sinf(r2);
    float dr  = r1 - r2;
    float cd  = __cosf(dr), sd = __sinf(dr);
    float ddx = x1 - x2, ddy = y1 - y2;
    float tx  = fmaf(c2v, ddx,  s2v * ddy);
    float ty  = fmaf(-s2v, ddx, c2v * ddy);

    // P half-edge vectors in Q frame
    float ux_ = h1x * cd,  uy_ = h1x * sd;
    float vx_ = -h1y * sd, vy_ = h1y * cd;
    // full edge vectors ±2u, ±2v and their shared reciprocals
    float eux = 2.0f * ux_, euy = 2.0f * uy_;
    float evx = 2.0f * vx_, evy = 2.0f * vy_;
    float ruxP = __fdividef(1.0f, clamp_mag(eux));
    float ruyP = __fdividef(1.0f, clamp_mag(euy));
    float rvxP = __fdividef(1.0f, clamp_mag(evx));
    float rvyP = __fdividef(1.0f, clamp_mag(evy));
    // corners (CCW)
    float p0x = tx + ux_ + vx_, p0y = ty + uy_ + vy_;
    float p1x = tx - ux_ + vx_, p1y = ty - uy_ + vy_;
    float p2x = tx - ux_ - vx_, p2y = ty - uy_ - vy_;
    float p3x = tx + ux_ - vx_, p3y = ty + uy_ - vy_;

    float area2 = 0.0f, dDx = 0.0f, dDy = 0.0f;
    edge_piece(p0x, p0y, -eux, -euy, -ruxP, -ruyP, h2x, h2y, area2, dDx, dDy);
    edge_piece(p1x, p1y, -evx, -evy, -rvxP, -rvyP, h2x, h2y, area2, dDx, dDy);
    edge_piece(p2x, p2y,  eux,  euy,  ruxP,  ruyP, h2x, h2y, area2, dDx, dDy);
    edge_piece(p3x, p3y,  evx,  evy,  rvxP,  rvyP, h2x, h2y, area2, dDx, dDy);

    // Q in P's frame: u' = R^T·(h2x,0), v' = R^T·(0,h2y), o = -R^T·t
    float upx = h2x * cd,  upy = -h2x * sd;
    float vpx = h2y * sd,  vpy = h2y * cd;
    float ox  = -(fmaf(cd, tx,  sd * ty));
    float oy  = -(fmaf(-sd, tx, cd * ty));
    float equx = 2.0f * upx, equy = 2.0f * upy;
    float eqvx = 2.0f * vpx, eqvy = 2.0f * vpy;
    float ruxQ = __fdividef(1.0f, clamp_mag(equx));
    float ruyQ = __fdividef(1.0f, clamp_mag(equy));
    float rvxQ = __fdividef(1.0f, clamp_mag(eqvx));
    float rvyQ = __fdividef(1.0f, clamp_mag(eqvy));
    float q0x = ox + upx + vpx, q0y = oy + upy + vpy;
    float q1x = ox - upx + vpx, q1y = oy - upy + vpy;
    float q2x = ox - upx - vpx, q2y = oy - upy - vpy;
    float q3x = ox + upx - vpx, q3y = oy + upy - vpy;

    float Dx = 0.0f, Dy = 0.0f;
    edge_piece(q0x, q0y, -equx, -equy, -ruxQ, -ruyQ, h1x, h1y, area2, Dx, Dy);
    edge_piece(q1x, q1y, -eqvx, -eqvy, -rvxQ, -rvyQ, h1x, h1y, area2, Dx, Dy);
    edge_piece(q2x, q2y,  equx,  equy,  ruxQ,  ruyQ, h1x, h1y, area2, Dx, Dy);
    edge_piece(q3x, q3y,  eqvx,  eqvy,  rvxQ,  rvyQ, h1x, h1y, area2, Dx, Dy);

    // translation correction: cross(t, R·D)
    float RDx = fmaf(cd, Dx, -(sd * Dy));
    float RDy = fmaf(sd, Dx,   cd * Dy);
    area2 += fmaf(tx, RDy, -(ty * RDx));

    float inter = 0.5f * fabsf(area2);
    float uni = fmaxf(a1 + a2 - inter, 1e-6f);
    float iou = __fdividef(inter, uni);

    float target = (oh > 0) ? iou : 0.0f;
    float z  = __fdividef(1.0f, 1.0f + __expf(-ip));   // sigmoid
    float pt = __logf(1.0f + __expf(z)) - z * target;  // logaddexp(0,z) - z*target
    return pt * w;
}

__global__ __launch_bounds__(BLK)
void iou_pred_loss_kernel(const float* __restrict__ iou_preds,
                          const int*   __restrict__ one_hot,
                          const float* __restrict__ weights,
                          const float* __restrict__ anchors,
                          const float* __restrict__ box_preds,
                          const float* __restrict__ reg_targets,
                          float* __restrict__ out,
                          int N, int B)
{
    int tid   = threadIdx.x;
    int n_idx = blockIdx.x * BLK + tid;
    if (n_idx >= N) return;

    int yspan = gridDim.y;                 // = ceil(B/2)
    int b0 = blockIdx.y;
    int b1 = blockIdx.y + yspan;
    bool has2 = (b1 < B);
    size_t g0 = (size_t)b0 * N + n_idx;
    size_t g1 = (size_t)(has2 ? b1 : b0) * N + n_idx;

    // ---- issue ALL global loads up front (MLP) ----
    const float* an = anchors + (size_t)n_idx * 7;
    float xa = an[0], ya = an[1], dxa = an[3], dya = an[4], ra = an[6];

    const float* bpp0 = box_preds   + g0 * 7;
    const float* rtp0 = reg_targets + g0 * 7;
    const float* bpp1 = box_preds   + g1 * 7;
    const float* rtp1 = reg_targets + g1 * 7;
    float bp0[5] = {bpp0[0], bpp0[1], bpp0[3], bpp0[4], bpp0[6]};
    float rt0[5] = {rtp0[0], rtp0[1], rtp0[3], rtp0[4], rtp0[6]};
    float bp1[5] = {bpp1[0], bpp1[1], bpp1[3], bpp1[4], bpp1[6]};
    float rt1[5] = {rtp1[0], rtp1[1], rtp1[3], rtp1[4], rtp1[6]};
    float ip0 = iou_preds[g0], ip1 = iou_preds[g1];
    int   oh0 = one_hot[g0],   oh1 = one_hot[g1];
    float w0  = weights[g0],   w1  = weights[g1];

    float diag = sqrtf(fmaf(dxa, dxa, dya * dya));

    out[g0] = pair_loss(bp0, rt0, xa, ya, dxa, dya, ra, diag, ip0, oh0, w0);
    if (has2)
        out[g1] = pair_loss(bp1, rt1, xa, ya, dxa, dya, ra, diag, ip1, oh1, w1);
}

extern "C" void kernel_launch(void* const* d_in, const int* in_sizes, int n_in,
                              void* d_out, int out_size, void* d_ws, size_t ws_size,
                              hipStream_t stream) {
    const float* iou_preds   = (const float*)d_in[0];
    const int*   one_hot     = (const int*)  d_in[1];
    const float* weights     = (const float*)d_in[2];
    const float* anchors     = (const float*)d_in[3];
    const float* box_preds   = (const float*)d_in[4];
    const float* reg_targets = (const float*)d_in[5];
    float* out = (float*)d_out;

    int total = in_sizes[0];       // B*N
    int N     = in_sizes[3] / 7;   // anchor count
    int B     = total / N;

    dim3 grid((N + BLK - 1) / BLK, (B + 1) / 2);
    iou_pred_loss_kernel<<<grid, dim3(BLK), 0, stream>>>(
        iou_preds, one_hot, weights, anchors, box_preds, reg_targets,
        out, N, B);
}